// Round 2
// baseline (194.576 us; speedup 1.0000x reference)
//
#include <hip/hip_runtime.h>
#include <math.h>

// Problem constants (fixed by reference setup_inputs)
#define BB 4096
#define LL 16
#define DD 512

#define LOG2E_F  1.4426950408889634f
#define LN2_F    0.6931471805599453f
#define LOG2PI_F 1.8378770664093453f

#if __has_builtin(__builtin_amdgcn_exp2f)
#define EXP2(x) __builtin_amdgcn_exp2f(x)
#else
#define EXP2(x) exp2f(x)
#endif
#if __has_builtin(__builtin_amdgcn_logf)
#define LOG2(x) __builtin_amdgcn_logf(x)
#else
#define LOG2(x) log2f(x)
#endif

// ---------------------------------------------------------------------------
// Kernel 1: per-(j,l) coefficient prep + KL reduction.
// lp2[i,j,l] = log2e * lp = A*z^2 + B*z + C with
//   A = -0.5*log2e*exp(-lv)
//   B = -2*A*m
//   C = A*m^2 - 0.5*log2e*(lv + log2pi)
// coef layout per j: [A0..A15][B0..B15][C0..C15]  (48 floats, 192B)
// ---------------------------------------------------------------------------
__global__ __launch_bounds__(256) void prep_kernel(
    const float* __restrict__ zm, const float* __restrict__ zlv,
    float* __restrict__ coef, float* __restrict__ out) {
  int idx = blockIdx.x * 256 + threadIdx.x;  // < B*L = 65536
  int j = idx >> 4;
  int l = idx & 15;
  float m = zm[idx];
  float lv = zlv[idx];
  float inv = EXP2(-lv * LOG2E_F);           // e^{-lv}
  float a = -0.5f * LOG2E_F * inv;
  float c2 = -0.5f * LOG2E_F * (lv + LOG2PI_F);
  coef[j * 48 + l]      = a;
  coef[j * 48 + 16 + l] = -2.0f * a * m;
  coef[j * 48 + 32 + l] = fmaf(a, m * m, c2);

  // KL summand: m^2 + e^{lv} - lv - 1
  float kls = m * m + EXP2(lv * LOG2E_F) - lv - 1.0f;
#pragma unroll
  for (int off = 32; off; off >>= 1) kls += __shfl_xor(kls, off);
  if ((threadIdx.x & 63) == 0) atomicAdd(out, kls * (0.5f / (float)BB));
}

// ---------------------------------------------------------------------------
// Kernel 2: recon loss = mean |data - recon| over B*D. BW-bound (16 MB).
// ---------------------------------------------------------------------------
__global__ __launch_bounds__(256) void recon_kernel(
    const float4* __restrict__ d, const float4* __restrict__ r,
    float* __restrict__ out) {
  const int n4 = (BB * DD) / 4;  // 524288
  int stride = gridDim.x * blockDim.x;
  float s = 0.0f;
  for (int k = blockIdx.x * blockDim.x + threadIdx.x; k < n4; k += stride) {
    float4 a = d[k];
    float4 b = r[k];
    s += fabsf(a.x - b.x) + fabsf(a.y - b.y) + fabsf(a.z - b.z) + fabsf(a.w - b.w);
  }
#pragma unroll
  for (int off = 32; off; off >>= 1) s += __shfl_xor(s, off);
  if ((threadIdx.x & 63) == 0) atomicAdd(out, s * (1.0f / (float)(BB * DD)));
}

// ---------------------------------------------------------------------------
// Kernel 3: total-correlation term.
// 256 blocks x 256 threads. Each wave owns 4 rows; lanes partition j.
// Unshifted logsumexp in base-2 domain (numerically safe here: max term of
// every LSE is >= ~2^-90, terms <= ~2^4).
// ---------------------------------------------------------------------------
__global__ __launch_bounds__(256, 1) void tc_kernel(
    const float* __restrict__ z, const float* __restrict__ coef,
    float* __restrict__ out) {
  __shared__ float zsh[256];
  const int tid = threadIdx.x;
  const int wave = tid >> 6;
  const int lane = tid & 63;
  const int rowbase = blockIdx.x * 16;  // 16 rows per block, 4 per wave

  zsh[tid] = z[rowbase * LL + tid];
  __syncthreads();
  const float* zw = &zsh[wave * 4 * LL];  // this wave's 4 rows

  float accL[4][16];
  float accJ[4];
#pragma unroll
  for (int r = 0; r < 4; ++r) {
    accJ[r] = 0.0f;
#pragma unroll
    for (int l = 0; l < 16; ++l) accL[r][l] = 0.0f;
  }

  const float* cp = coef + lane * 48;
  for (int jj = 0; jj < 64; ++jj) {
    float A[16], Bq[16], Cq[16];
#pragma unroll
    for (int q = 0; q < 4; ++q) {
      float4 va = *(const float4*)(cp + 4 * q);
      float4 vb = *(const float4*)(cp + 16 + 4 * q);
      float4 vc = *(const float4*)(cp + 32 + 4 * q);
      A[4 * q] = va.x;  A[4 * q + 1] = va.y;  A[4 * q + 2] = va.z;  A[4 * q + 3] = va.w;
      Bq[4 * q] = vb.x; Bq[4 * q + 1] = vb.y; Bq[4 * q + 2] = vb.z; Bq[4 * q + 3] = vb.w;
      Cq[4 * q] = vc.x; Cq[4 * q + 1] = vc.y; Cq[4 * q + 2] = vc.z; Cq[4 * q + 3] = vc.w;
    }
#pragma unroll
    for (int r = 0; r < 4; ++r) {
      float s0 = 0.0f, s1 = 0.0f, s2 = 0.0f, s3 = 0.0f;
#pragma unroll
      for (int l = 0; l < 16; ++l) {
        float zv = zw[r * 16 + l];
        float t = fmaf(A[l], zv, Bq[l]);
        float lp = fmaf(t, zv, Cq[l]);  // lp2 = log2e * log-density
        accL[r][l] += EXP2(lp);
        if ((l & 3) == 0) s0 += lp;
        else if ((l & 3) == 1) s1 += lp;
        else if ((l & 3) == 2) s2 += lp;
        else s3 += lp;
      }
      accJ[r] += EXP2((s0 + s1) + (s2 + s3));
    }
    cp += 64 * 48;
  }

  // Butterfly reduce the 68 accumulators across the wave (plain sums —
  // unshifted LSE makes partial sums exactly additive).
#pragma unroll
  for (int off = 32; off; off >>= 1) {
#pragma unroll
    for (int r = 0; r < 4; ++r) {
      accJ[r] += __shfl_xor(accJ[r], off);
#pragma unroll
      for (int l = 0; l < 16; ++l) accL[r][l] += __shfl_xor(accL[r][l], off);
    }
  }

  if (lane == 0) {
    float t = 0.0f;
#pragma unroll
    for (int r = 0; r < 4; ++r) {
      float lg = LOG2(accJ[r]);  // log2 S_joint
#pragma unroll
      for (int l = 0; l < 16; ++l) lg -= LOG2(accL[r][l]);
      t += lg;
    }
    // tc contribution: ln2 * (log2 Sj - sum log2 Sl), averaged over B
    atomicAdd(out, t * (LN2_F / (float)BB));
  }
}

extern "C" void kernel_launch(void* const* d_in, const int* in_sizes, int n_in,
                              void* d_out, int out_size, void* d_ws, size_t ws_size,
                              hipStream_t stream) {
  const float* data  = (const float*)d_in[0];
  const float* recon = (const float*)d_in[1];
  const float* z     = (const float*)d_in[2];
  const float* zm    = (const float*)d_in[3];
  const float* zlv   = (const float*)d_in[4];
  float* out = (float*)d_out;
  float* coef = (float*)d_ws;  // 4096 * 48 floats = 786432 B

  // All three loss terms atomically accumulate (pre-scaled) into out[0].
  (void)hipMemsetAsync(out, 0, sizeof(float), stream);
  hipLaunchKernelGGL(prep_kernel, dim3(BB * LL / 256), dim3(256), 0, stream,
                     zm, zlv, coef, out);
  hipLaunchKernelGGL(recon_kernel, dim3(512), dim3(256), 0, stream,
                     reinterpret_cast<const float4*>(data),
                     reinterpret_cast<const float4*>(recon), out);
  hipLaunchKernelGGL(tc_kernel, dim3(BB / 16), dim3(256), 0, stream,
                     z, coef, out);
}

// Round 3
// 170.222 us; speedup vs baseline: 1.1431x; 1.1431x over previous
//
#include <hip/hip_runtime.h>
#include <math.h>

// Problem constants (fixed by reference setup_inputs)
#define BB 4096
#define LL 16
#define DD 512

#define LOG2E_F  1.4426950408889634f
#define LN2_F    0.6931471805599453f
#define LOG2PI_F 1.8378770664093453f

#if __has_builtin(__builtin_amdgcn_exp2f)
#define EXP2(x) __builtin_amdgcn_exp2f(x)
#else
#define EXP2(x) exp2f(x)
#endif
#if __has_builtin(__builtin_amdgcn_logf)
#define LOG2(x) __builtin_amdgcn_logf(x)
#else
#define LOG2(x) log2f(x)
#endif

// ws float layout:
//   coef    [0      , 196608)   4096 j * 48  (A[16] B[16] C[16] per j)
//   rp      [196608 , 196864)   256 recon block partials (pre-scaled)
//   klp     [196864 , 197120)   256 KL block partials (pre-scaled)
//   partial [197120 , +nc*17*4096)  tc partials, [(c*17+k)*4096 + i], k=16 is joint
#define COEF_F   0
#define RP_F     196608
#define KLP_F    196864
#define PART_F   197120

// Block-level sum reduction; result valid on thread 0.
__device__ __forceinline__ float block_reduce(float v) {
  __shared__ float sm[4];
#pragma unroll
  for (int off = 32; off; off >>= 1) v += __shfl_xor(v, off);
  if ((threadIdx.x & 63) == 0) sm[threadIdx.x >> 6] = v;
  __syncthreads();
  if (threadIdx.x == 0) v = (sm[0] + sm[1]) + (sm[2] + sm[3]);
  return v;
}

// ---------------------------------------------------------------------------
// Kernel 1: per-(j,l) coefficient prep + KL block partials (no atomics).
// lp2 = log2e * log-density = A*z^2 + B*z + C
// ---------------------------------------------------------------------------
__global__ __launch_bounds__(256) void prep_kernel(
    const float* __restrict__ zm, const float* __restrict__ zlv,
    float* __restrict__ coef, float* __restrict__ klp) {
  int idx = blockIdx.x * 256 + threadIdx.x;  // < B*L = 65536
  int j = idx >> 4;
  int l = idx & 15;
  float m = zm[idx];
  float lv = zlv[idx];
  float inv = EXP2(-lv * LOG2E_F);           // e^{-lv}
  float a = -0.5f * LOG2E_F * inv;
  float c2 = -0.5f * LOG2E_F * (lv + LOG2PI_F);
  coef[j * 48 + l]      = a;
  coef[j * 48 + 16 + l] = -2.0f * a * m;
  coef[j * 48 + 32 + l] = fmaf(a, m * m, c2);

  float kls = m * m + EXP2(lv * LOG2E_F) - lv - 1.0f;  // KL summand
  float s = block_reduce(kls);
  if (threadIdx.x == 0) klp[blockIdx.x] = s * (0.5f / (float)BB);
}

// ---------------------------------------------------------------------------
// Kernel 2: recon loss partials (256 blocks, no atomics).
// ---------------------------------------------------------------------------
__global__ __launch_bounds__(256) void recon_kernel(
    const float4* __restrict__ d, const float4* __restrict__ r,
    float* __restrict__ rp) {
  const int n4 = (BB * DD) / 4;  // 524288
  int stride = gridDim.x * blockDim.x;
  float s = 0.0f;
  for (int k = blockIdx.x * blockDim.x + threadIdx.x; k < n4; k += stride) {
    float4 a = d[k];
    float4 b = r[k];
    s += (fabsf(a.x - b.x) + fabsf(a.y - b.y)) +
         (fabsf(a.z - b.z) + fabsf(a.w - b.w));
  }
  float t = block_reduce(s);
  if (threadIdx.x == 0) rp[blockIdx.x] = t * (1.0f / (float)(BB * DD));
}

// ---------------------------------------------------------------------------
// Kernel 3: TC partial sums. Row-per-lane; j-loop is wave-uniform so coef
// reads are scalar (SGPR broadcast). Joint term = product of the 16 per-l
// exps (no extra transcendental). Unshifted base-2 LSE — partials are plain
// sums, exactly additive across chunk blocks.
// grid = (16 row-blocks, nc j-chunks), 256 threads.
// ---------------------------------------------------------------------------
__global__ __launch_bounds__(256, 4) void tc_kernel(
    const float* __restrict__ z, const float* __restrict__ coef,
    float* __restrict__ partial, int nc) {
  const int tid = threadIdx.x;
  const int i = blockIdx.x * 256 + tid;  // this lane's row
  const int chunk = BB / nc;
  const int j0 = blockIdx.y * chunk;

  float zv[16];
  const float4* zp = (const float4*)(z + i * 16);
#pragma unroll
  for (int q = 0; q < 4; ++q) {
    float4 v = zp[q];
    zv[4 * q] = v.x; zv[4 * q + 1] = v.y; zv[4 * q + 2] = v.z; zv[4 * q + 3] = v.w;
  }

  float accL[16];
  float accJ = 0.0f;
#pragma unroll
  for (int l = 0; l < 16; ++l) accL[l] = 0.0f;

  const float* cp = coef + (size_t)j0 * 48;
  for (int j = 0; j < chunk; ++j) {
    float p0 = 1.0f, p1 = 1.0f, p2 = 1.0f, p3 = 1.0f;
#pragma unroll
    for (int l = 0; l < 16; ++l) {
      // lp2 = A*z^2 + B*z + C  (A,B,C wave-uniform -> scalar loads)
      float lp = fmaf(fmaf(cp[l], zv[l], cp[16 + l]), zv[l], cp[32 + l]);
      float e = EXP2(lp);
      accL[l] += e;
      if ((l & 3) == 0) p0 *= e;
      else if ((l & 3) == 1) p1 *= e;
      else if ((l & 3) == 2) p2 *= e;
      else p3 *= e;
    }
    accJ += (p0 * p1) * (p2 * p3);  // = exp2(sum_l lp2)
    cp += 48;
  }

  float* base = partial + ((size_t)blockIdx.y * 17) * BB + i;
#pragma unroll
  for (int k = 0; k < 16; ++k) base[(size_t)k * BB] = accL[k];
  base[(size_t)16 * BB] = accJ;
}

// ---------------------------------------------------------------------------
// Kernel 4: finalize. 16 blocks x 256; thread -> row. Reduce chunks, take
// logs, fold in recon/KL partials, 16 atomics total into out[0].
// ---------------------------------------------------------------------------
__global__ __launch_bounds__(256) void final_kernel(
    const float* __restrict__ partial, const float* __restrict__ rp,
    const float* __restrict__ klp, float* __restrict__ out, int nc) {
  const int tid = threadIdx.x;
  const int i = blockIdx.x * 256 + tid;

  float sL[16];
  float sJ = 0.0f;
#pragma unroll
  for (int k = 0; k < 16; ++k) sL[k] = 0.0f;
  for (int c = 0; c < nc; ++c) {
    const float* b = partial + ((size_t)c * 17) * BB + i;
#pragma unroll
    for (int k = 0; k < 16; ++k) sL[k] += b[(size_t)k * BB];
    sJ += b[(size_t)16 * BB];
  }
  float lg = LOG2(sJ);
#pragma unroll
  for (int k = 0; k < 16; ++k) lg -= LOG2(sL[k]);
  float t = lg * (LN2_F / (float)BB);  // tc contribution of row i

  if (blockIdx.x == 0) t += rp[tid] + klp[tid];  // fold in 256+256 partials

  float s = block_reduce(t);
  if (tid == 0) atomicAdd(out, s);
}

extern "C" void kernel_launch(void* const* d_in, const int* in_sizes, int n_in,
                              void* d_out, int out_size, void* d_ws, size_t ws_size,
                              hipStream_t stream) {
  const float* data  = (const float*)d_in[0];
  const float* recon = (const float*)d_in[1];
  const float* z     = (const float*)d_in[2];
  const float* zm    = (const float*)d_in[3];
  const float* zlv   = (const float*)d_in[4];
  float* out = (float*)d_out;
  float* ws  = (float*)d_ws;

  // Pick largest power-of-2 chunk count whose partial buffer fits in ws.
  int nc = 64;
  while (nc > 1 && ((size_t)PART_F + (size_t)nc * 17 * BB) * 4 > ws_size) nc >>= 1;

  float* coef = ws + COEF_F;
  float* rp   = ws + RP_F;
  float* klp  = ws + KLP_F;
  float* part = ws + PART_F;

  (void)hipMemsetAsync(out, 0, sizeof(float), stream);
  hipLaunchKernelGGL(prep_kernel, dim3(BB * LL / 256), dim3(256), 0, stream,
                     zm, zlv, coef, klp);
  hipLaunchKernelGGL(recon_kernel, dim3(256), dim3(256), 0, stream,
                     reinterpret_cast<const float4*>(data),
                     reinterpret_cast<const float4*>(recon), rp);
  hipLaunchKernelGGL(tc_kernel, dim3(BB / 256, nc), dim3(256), 0, stream,
                     z, coef, part, nc);
  hipLaunchKernelGGL(final_kernel, dim3(BB / 256), dim3(256), 0, stream,
                     part, rp, klp, out, nc);
}

// Round 4
// 146.265 us; speedup vs baseline: 1.3303x; 1.1638x over previous
//
#include <hip/hip_runtime.h>
#include <math.h>

// Problem constants (fixed by reference setup_inputs)
#define BB 4096
#define LL 16
#define DD 512

#define LOG2E_F  1.4426950408889634f
#define LN2_F    0.6931471805599453f
#define LOG2PI_F 1.8378770664093453f

#if __has_builtin(__builtin_amdgcn_exp2f)
#define EXP2(x) __builtin_amdgcn_exp2f(x)
#else
#define EXP2(x) exp2f(x)
#endif
#if __has_builtin(__builtin_amdgcn_logf)
#define LOG2(x) __builtin_amdgcn_logf(x)
#else
#define LOG2(x) log2f(x)
#endif

// ws float layout:
//   coef    [0      , 196608)   4096 j * 48  (A[16] B[16] C[16] per j)
//   rp      [196608 , 196864)   256 recon block partials (pre-scaled)
//   klp     [196864 , 197120)   256 KL block partials (pre-scaled)
//   reduced [197120 , 266752)   17 * 4096  (k-major; k=16 is joint)
//   partial [266752 , +nc*17*4096)  tc partials, [(c*17+k)*4096 + i]
#define COEF_F   0
#define RP_F     196608
#define KLP_F    196864
#define RED_F    197120
#define PART_F   266752

// Block-level sum reduction; result valid on thread 0.
__device__ __forceinline__ float block_reduce(float v) {
  __shared__ float sm[4];
#pragma unroll
  for (int off = 32; off; off >>= 1) v += __shfl_xor(v, off);
  if ((threadIdx.x & 63) == 0) sm[threadIdx.x >> 6] = v;
  __syncthreads();
  if (threadIdx.x == 0) v = (sm[0] + sm[1]) + (sm[2] + sm[3]);
  return v;
}

// ---------------------------------------------------------------------------
// Kernel 1: per-(j,l) coefficient prep + KL block partials (no atomics).
// lp2 = log2e * log-density = A*z^2 + B*z + C
// ---------------------------------------------------------------------------
__global__ __launch_bounds__(256) void prep_kernel(
    const float* __restrict__ zm, const float* __restrict__ zlv,
    float* __restrict__ coef, float* __restrict__ klp) {
  int idx = blockIdx.x * 256 + threadIdx.x;  // < B*L = 65536
  int j = idx >> 4;
  int l = idx & 15;
  float m = zm[idx];
  float lv = zlv[idx];
  float inv = EXP2(-lv * LOG2E_F);           // e^{-lv}
  float a = -0.5f * LOG2E_F * inv;
  float c2 = -0.5f * LOG2E_F * (lv + LOG2PI_F);
  coef[j * 48 + l]      = a;
  coef[j * 48 + 16 + l] = -2.0f * a * m;
  coef[j * 48 + 32 + l] = fmaf(a, m * m, c2);

  float kls = m * m + EXP2(lv * LOG2E_F) - lv - 1.0f;  // KL summand
  float s = block_reduce(kls);
  if (threadIdx.x == 0) klp[blockIdx.x] = s * (0.5f / (float)BB);
}

// ---------------------------------------------------------------------------
// Kernel 2: recon loss partials (256 blocks, no atomics).
// ---------------------------------------------------------------------------
__global__ __launch_bounds__(256) void recon_kernel(
    const float4* __restrict__ d, const float4* __restrict__ r,
    float* __restrict__ rp) {
  const int n4 = (BB * DD) / 4;  // 524288
  int stride = gridDim.x * blockDim.x;
  float s = 0.0f;
  for (int k = blockIdx.x * blockDim.x + threadIdx.x; k < n4; k += stride) {
    float4 a = d[k];
    float4 b = r[k];
    s += (fabsf(a.x - b.x) + fabsf(a.y - b.y)) +
         (fabsf(a.z - b.z) + fabsf(a.w - b.w));
  }
  float t = block_reduce(s);
  if (threadIdx.x == 0) rp[blockIdx.x] = t * (1.0f / (float)(BB * DD));
}

// ---------------------------------------------------------------------------
// Kernel 3: TC partial sums. Row-per-lane; j-loop is wave-uniform so coef
// reads are scalar (SGPR broadcast). Joint term = product of the 16 per-l
// exps. Unshifted base-2 LSE — partials exactly additive across chunks.
// grid = (16 row-blocks, nc j-chunks). VGPR=36 last round, so 8 waves/EU
// is safe — (256,8) lets 8 blocks/CU co-reside to hide exp/s_load latency.
// ---------------------------------------------------------------------------
__global__ __launch_bounds__(256, 8) void tc_kernel(
    const float* __restrict__ z, const float* __restrict__ coef,
    float* __restrict__ partial, int nc) {
  const int tid = threadIdx.x;
  const int i = blockIdx.x * 256 + tid;  // this lane's row
  const int chunk = BB / nc;
  const int j0 = blockIdx.y * chunk;

  float zv[16];
  const float4* zp = (const float4*)(z + i * 16);
#pragma unroll
  for (int q = 0; q < 4; ++q) {
    float4 v = zp[q];
    zv[4 * q] = v.x; zv[4 * q + 1] = v.y; zv[4 * q + 2] = v.z; zv[4 * q + 3] = v.w;
  }

  float accL[16];
  float accJ = 0.0f;
#pragma unroll
  for (int l = 0; l < 16; ++l) accL[l] = 0.0f;

  const float* cp = coef + (size_t)j0 * 48;
  for (int j = 0; j < chunk; ++j) {
    float p0 = 1.0f, p1 = 1.0f, p2 = 1.0f, p3 = 1.0f;
#pragma unroll
    for (int l = 0; l < 16; ++l) {
      // lp2 = A*z^2 + B*z + C  (A,B,C wave-uniform -> scalar loads)
      float lp = fmaf(fmaf(cp[l], zv[l], cp[16 + l]), zv[l], cp[32 + l]);
      float e = EXP2(lp);
      accL[l] += e;
      if ((l & 3) == 0) p0 *= e;
      else if ((l & 3) == 1) p1 *= e;
      else if ((l & 3) == 2) p2 *= e;
      else p3 *= e;
    }
    accJ += (p0 * p1) * (p2 * p3);  // = exp2(sum_l lp2)
    cp += 48;
  }

  float* base = partial + ((size_t)blockIdx.y * 17) * BB + i;
#pragma unroll
  for (int k = 0; k < 16; ++k) base[(size_t)k * BB] = accL[k];
  base[(size_t)16 * BB] = accJ;
}

// ---------------------------------------------------------------------------
// Kernel 4 (stage A): reduce partials over chunks. grid (16 row-blocks, 17 k).
// 272 blocks -> full-device BW instead of R3's 16-block latency crawl.
// ---------------------------------------------------------------------------
__global__ __launch_bounds__(256) void reduce_kernel(
    const float* __restrict__ partial, float* __restrict__ reduced, int nc) {
  const int i = blockIdx.x * 256 + threadIdx.x;
  const int k = blockIdx.y;
  const float* p = partial + (size_t)k * BB + i;
  const size_t cstride = (size_t)17 * BB;
  float s0 = 0.0f, s1 = 0.0f, s2 = 0.0f, s3 = 0.0f;
  int c = 0;
  for (; c + 4 <= nc; c += 4) {  // 4 loads in flight per round
    s0 += p[(size_t)(c + 0) * cstride];
    s1 += p[(size_t)(c + 1) * cstride];
    s2 += p[(size_t)(c + 2) * cstride];
    s3 += p[(size_t)(c + 3) * cstride];
  }
  for (; c < nc; ++c) s0 += p[(size_t)c * cstride];
  reduced[(size_t)k * BB + i] = (s0 + s1) + (s2 + s3);
}

// ---------------------------------------------------------------------------
// Kernel 5 (stage B): logs + fold recon/KL partials. Reads 278 KB (L2-warm).
// ---------------------------------------------------------------------------
__global__ __launch_bounds__(256) void final_kernel(
    const float* __restrict__ reduced, const float* __restrict__ rp,
    const float* __restrict__ klp, float* __restrict__ out) {
  const int tid = threadIdx.x;
  const int i = blockIdx.x * 256 + tid;

  float lg = LOG2(reduced[(size_t)16 * BB + i]);  // log2 S_joint
#pragma unroll
  for (int k = 0; k < 16; ++k) lg -= LOG2(reduced[(size_t)k * BB + i]);
  float t = lg * (LN2_F / (float)BB);  // tc contribution of row i

  if (blockIdx.x == 0) t += rp[tid] + klp[tid];  // fold 256+256 partials

  float s = block_reduce(t);
  if (tid == 0) atomicAdd(out, s);
}

extern "C" void kernel_launch(void* const* d_in, const int* in_sizes, int n_in,
                              void* d_out, int out_size, void* d_ws, size_t ws_size,
                              hipStream_t stream) {
  const float* data  = (const float*)d_in[0];
  const float* recon = (const float*)d_in[1];
  const float* z     = (const float*)d_in[2];
  const float* zm    = (const float*)d_in[3];
  const float* zlv   = (const float*)d_in[4];
  float* out = (float*)d_out;
  float* ws  = (float*)d_ws;

  // Largest power-of-2 chunk count whose partial buffer fits in ws.
  int nc = 128;
  while (nc > 8 && ((size_t)PART_F + (size_t)nc * 17 * BB) * 4 > ws_size) nc >>= 1;

  float* coef = ws + COEF_F;
  float* rp   = ws + RP_F;
  float* klp  = ws + KLP_F;
  float* red  = ws + RED_F;
  float* part = ws + PART_F;

  (void)hipMemsetAsync(out, 0, sizeof(float), stream);
  hipLaunchKernelGGL(prep_kernel, dim3(BB * LL / 256), dim3(256), 0, stream,
                     zm, zlv, coef, klp);
  hipLaunchKernelGGL(recon_kernel, dim3(256), dim3(256), 0, stream,
                     reinterpret_cast<const float4*>(data),
                     reinterpret_cast<const float4*>(recon), rp);
  hipLaunchKernelGGL(tc_kernel, dim3(BB / 256, nc), dim3(256), 0, stream,
                     z, coef, part, nc);
  hipLaunchKernelGGL(reduce_kernel, dim3(BB / 256, 17), dim3(256), 0, stream,
                     part, red, nc);
  hipLaunchKernelGGL(final_kernel, dim3(BB / 256), dim3(256), 0, stream,
                     red, rp, klp, out);
}